// Round 4
// baseline (319.667 us; speedup 1.0000x reference)
//
#include <hip/hip_runtime.h>

#define T_DEPTH 200000
#define V_DIM   130
#define H_DIM   512

// d_out offsets (fp32 elements): ot, Val, stg, rt, h_new, c_new
#define OT_OFF   0
#define VAL_OFF  512
#define STG_OFF  26000642
#define RT_OFF   26200643
#define HN_OFF   26200773
#define CN_OFF   26201797

#define CHAIN_BLOCKS 64
#define COPY_BLOCKS  256
#define GRID_BLOCKS  (CHAIN_BLOCKS + COPY_BLOCKS)

// ws layout: ints [0..15] barrier counters, int [16] istop, floats after
#define WS_ISTOP  16
#define WS_G0     32          // 2048 floats
#define WS_G1     2080        // 2048 floats
#define WS_VT     4160        // 130 floats
#define WS_DTUT   4300        // 2 floats

typedef float fvec4 __attribute__((ext_vector_type(4)));

static __device__ __forceinline__ float sigmoidf(float x) {
    return 1.0f / (1.0f + expf(-x));
}

// sub-grid barrier among the CHAIN_BLOCKS blocks; distinct counter per phase
static __device__ __forceinline__ void gbar(int* bar) {
    __syncthreads();
    if (threadIdx.x == 0) {
        __hip_atomic_fetch_add(bar, 1, __ATOMIC_RELEASE, __HIP_MEMORY_SCOPE_AGENT);
        while (__hip_atomic_load(bar, __ATOMIC_ACQUIRE, __HIP_MEMORY_SCOPE_AGENT)
               < CHAIN_BLOCKS)
            __builtin_amdgcn_s_sleep(8);
    }
    __syncthreads();
}

__global__ __launch_bounds__(256) void k_fused(
        const float* __restrict__ input, const float* __restrict__ prev_Val,
        const float* __restrict__ prev_stg, const float* __restrict__ prev_read,
        const float* __restrict__ prev_h, const float* __restrict__ prev_c,
        const float* __restrict__ W_ih0, const float* __restrict__ W_hh0,
        const float* __restrict__ b_ih0, const float* __restrict__ b_hh0,
        const float* __restrict__ W_ih1, const float* __restrict__ W_hh1,
        const float* __restrict__ b_ih1, const float* __restrict__ b_hh1,
        const float* __restrict__ Wd, const float* __restrict__ Bd,
        const float* __restrict__ Wu, const float* __restrict__ Bu,
        const float* __restrict__ Wv, const float* __restrict__ Bv,
        const float* __restrict__ Wo, const float* __restrict__ Bo,
        float* __restrict__ out, int* __restrict__ wsi, float* __restrict__ wsf) {

    const int b = blockIdx.x;
    const int t = threadIdx.x;

    // ---------------- copy blocks: stream prev_Val -> Val rows [0,T) ----------------
    if (b >= CHAIN_BLOCKS) {
        const int cb = b - CHAIN_BLOCKS;
        const fvec4* __restrict__ vi = (const fvec4*)prev_Val;
        fvec4* __restrict__ vo = (fvec4*)(out + VAL_OFF);       // 16B aligned
        const int NV4 = (T_DEPTH * V_DIM) / 4;                  // 6,500,000
        for (int idx = cb * 256 + t; idx < NV4; idx += COPY_BLOCKS * 256) {
            fvec4 v = __builtin_nontemporal_load(&vi[idx]);
            __builtin_nontemporal_store(v, &vo[idx]);
        }
        return;
    }

    // ---------------- chain blocks ----------------
    __shared__ float sh_h1[H_DIM];
    __shared__ float sh_h2[H_DIM];
    const int wave = t >> 6, lane = t & 63;

    // P0: g0[row] = Wih0[row,:]·(input+prev_read) + Whh0[row,:]·h_prev0 + b
    {
        const float* h0 = prev_h;           // layer 0 prev hidden
        for (int r = 0; r < 8; ++r) {
            int row = (b * 4 + wave) + 256 * r;   // 2048 rows total
            const float* wr = W_ih0 + row * V_DIM;
            const float* wh = W_hh0 + row * H_DIM;
            float p = 0.f;
            for (int c = lane; c < V_DIM; c += 64) p += wr[c] * (input[c] + prev_read[c]);
            for (int k = lane; k < H_DIM; k += 64) p += wh[k] * h0[k];
            for (int off = 32; off; off >>= 1) p += __shfl_down(p, off, 64);
            if (lane == 0) wsf[WS_G0 + row] = p + b_ih0[row] + b_hh0[row];
        }
    }
    gbar(&wsi[0]);

    // P1: cell0 (redundant per block) -> sh_h1 ; then g1 -> ws
    {
        const float* g0 = wsf + WS_G0;
        for (int r = 0; r < 2; ++r) {
            int j = t + 256 * r;
            float ig = sigmoidf(g0[j]);
            float fg = sigmoidf(g0[H_DIM + j]);
            float gg = tanhf(g0[2 * H_DIM + j]);
            float og = sigmoidf(g0[3 * H_DIM + j]);
            float cn = fg * prev_c[j] + ig * gg;
            float hn = og * tanhf(cn);
            sh_h1[j] = hn;
            if (b == 0) { out[HN_OFF + j] = hn; out[CN_OFF + j] = cn; }
        }
        __syncthreads();
        const float* h1p = prev_h + H_DIM;  // layer 1 prev hidden
        for (int r = 0; r < 8; ++r) {
            int row = (b * 4 + wave) + 256 * r;
            const float* wr = W_ih1 + row * H_DIM;
            const float* wh = W_hh1 + row * H_DIM;
            float p = 0.f;
            for (int k = lane; k < H_DIM; k += 64) p += wr[k] * sh_h1[k] + wh[k] * h1p[k];
            for (int off = 32; off; off >>= 1) p += __shfl_down(p, off, 64);
            if (lane == 0) wsf[WS_G1 + row] = p + b_ih1[row] + b_hh1[row];
        }
    }
    gbar(&wsi[1]);

    // P2: heads (blocks 0..3 only); each computes cell1 redundantly -> sh_h2
    if (b < 4) {
        const float* g1 = wsf + WS_G1;
        const float* c1p = prev_c + H_DIM;
        for (int r = 0; r < 2; ++r) {
            int j = t + 256 * r;
            float ig = sigmoidf(g1[j]);
            float fg = sigmoidf(g1[H_DIM + j]);
            float gg = tanhf(g1[2 * H_DIM + j]);
            float og = sigmoidf(g1[3 * H_DIM + j]);
            float cn = fg * c1p[j] + ig * gg;
            float hn = og * tanhf(cn);
            sh_h2[j] = hn;
            if (b == 0) { out[HN_OFF + H_DIM + j] = hn; out[CN_OFF + H_DIM + j] = cn; }
        }
        __syncthreads();

        if (b <= 1) {
            // ot[j] = tanh(sum_k h2[k]*Wo[k,j] + Bo[j]); coalesced over j
            int j = b * 256 + t;
            float a0 = 0.f, a1 = 0.f, a2 = 0.f, a3 = 0.f;
            for (int k = 0; k < H_DIM; k += 4) {
                a0 += sh_h2[k]     * Wo[(k)     * H_DIM + j];
                a1 += sh_h2[k + 1] * Wo[(k + 1) * H_DIM + j];
                a2 += sh_h2[k + 2] * Wo[(k + 2) * H_DIM + j];
                a3 += sh_h2[k + 3] * Wo[(k + 3) * H_DIM + j];
            }
            out[OT_OFF + j] = tanhf(a0 + a1 + a2 + a3 + Bo[j]);
        } else if (b == 2) {
            // vt[c] = tanh(sum_k h2[k]*Wv[k,c] + Bv[c])
            if (t < V_DIM) {
                float a0 = 0.f, a1 = 0.f, a2 = 0.f, a3 = 0.f;
                for (int k = 0; k < H_DIM; k += 4) {
                    a0 += sh_h2[k]     * Wv[(k)     * V_DIM + t];
                    a1 += sh_h2[k + 1] * Wv[(k + 1) * V_DIM + t];
                    a2 += sh_h2[k + 2] * Wv[(k + 2) * V_DIM + t];
                    a3 += sh_h2[k + 3] * Wv[(k + 3) * V_DIM + t];
                }
                float v = tanhf(a0 + a1 + a2 + a3 + Bv[t]);
                wsf[WS_VT + t] = v;
                out[VAL_OFF + (size_t)T_DEPTH * V_DIM + t] = v;  // Val row T
            }
        } else {
            // b == 3: dt (wave 0), ut (wave 1)
            if (wave < 2) {
                const float* w = (wave == 0) ? Wd : Wu;
                float p = 0.f;
                for (int k = lane; k < H_DIM; k += 64) p += sh_h2[k] * w[k];
                for (int off = 32; off; off >>= 1) p += __shfl_down(p, off, 64);
                if (lane == 0) {
                    if (wave == 0) {
                        float dt = sigmoidf(p + Bd[0]);
                        wsf[WS_DTUT + 0] = dt;
                        out[STG_OFF + T_DEPTH] = dt;   // stg[T] = dt
                    } else {
                        wsf[WS_DTUT + 1] = sigmoidf(p + Bu[0]);
                    }
                }
            }
        }
    }
    gbar(&wsi[2]);

    // P3: top-of-stack walk (block 0): exact pop head rewrite + rt
    if (b == 0) {
        float dt = wsf[WS_DTUT + 0];
        float u  = wsf[WS_DTUT + 1];
        float r  = 1.0f;
        float acc = 0.f;
        {   // i = T (freshly pushed row)
            float coef = fminf(dt, fmaxf(0.f, r));
            if (t < V_DIM) acc += coef * wsf[WS_VT + t];
            r -= dt;
        }
        int last = T_DEPTH;
        for (int i = T_DEPTH - 1; i >= 0; --i) {
            bool pa = (u > 0.f);
            if (!pa && r <= 0.f) break;       // below: stg = plain copy, coef = 0
            float s  = prev_stg[i];           // wave-uniform load
            float sn = fmaxf(0.f, s - fmaxf(0.f, u));
            u -= sn;
            if (pa) { if (t == 0) out[STG_OFF + i] = sn; last = i; }
            float coef = fminf(sn, fmaxf(0.f, r));
            r -= sn;
            if (coef > 0.f && t < V_DIM) acc += coef * prev_Val[(size_t)i * V_DIM + t];
        }
        if (t < V_DIM) out[RT_OFF + t] = acc;
        if (t == 0) __hip_atomic_store(&wsi[WS_ISTOP], last, __ATOMIC_RELEASE,
                                       __HIP_MEMORY_SCOPE_AGENT);
    }
    gbar(&wsi[3]);

    // P4: bulk stg copy [0, istop) by all chain blocks (float2; STG_OFF is 8B-aligned)
    {
        int istop = __hip_atomic_load(&wsi[WS_ISTOP], __ATOMIC_ACQUIRE,
                                      __HIP_MEMORY_SCOPE_AGENT);
        const float2* __restrict__ si = (const float2*)prev_stg;
        float2* __restrict__ so = (float2*)(out + STG_OFF);
        int np = istop >> 1;
        for (int idx = b * 256 + t; idx < np; idx += CHAIN_BLOCKS * 256)
            so[idx] = si[idx];
        if (b == 0 && t == 0 && (istop & 1))
            out[STG_OFF + istop - 1] = prev_stg[istop - 1];
    }
}

extern "C" void kernel_launch(void* const* d_in, const int* in_sizes, int n_in,
                              void* d_out, int out_size, void* d_ws, size_t ws_size,
                              hipStream_t stream) {
    (void)in_sizes; (void)n_in; (void)out_size; (void)ws_size;
    const float* input     = (const float*)d_in[0];
    const float* prev_Val  = (const float*)d_in[1];
    const float* prev_stg  = (const float*)d_in[2];
    const float* prev_read = (const float*)d_in[3];
    const float* prev_h    = (const float*)d_in[4];
    const float* prev_c    = (const float*)d_in[5];
    const float* W_ih0 = (const float*)d_in[6];
    const float* W_hh0 = (const float*)d_in[7];
    const float* b_ih0 = (const float*)d_in[8];
    const float* b_hh0 = (const float*)d_in[9];
    const float* W_ih1 = (const float*)d_in[10];
    const float* W_hh1 = (const float*)d_in[11];
    const float* b_ih1 = (const float*)d_in[12];
    const float* b_hh1 = (const float*)d_in[13];
    const float* Wd = (const float*)d_in[14];
    const float* Bd = (const float*)d_in[15];
    const float* Wu = (const float*)d_in[16];
    const float* Bu = (const float*)d_in[17];
    const float* Wv = (const float*)d_in[18];
    const float* Bv = (const float*)d_in[19];
    const float* Wo = (const float*)d_in[20];
    const float* Bo = (const float*)d_in[21];

    float* out = (float*)d_out;
    int*   wsi = (int*)d_ws;
    float* wsf = (float*)d_ws;

    // zero barrier counters (+istop slot); ws is poisoned 0xAA before every launch
    (void)hipMemsetAsync(d_ws, 0, 256, stream);

    k_fused<<<GRID_BLOCKS, 256, 0, stream>>>(
        input, prev_Val, prev_stg, prev_read, prev_h, prev_c,
        W_ih0, W_hh0, b_ih0, b_hh0, W_ih1, W_hh1, b_ih1, b_hh1,
        Wd, Bd, Wu, Bu, Wv, Bv, Wo, Bo, out, wsi, wsf);
}